// Round 10
// baseline (192.662 us; speedup 1.0000x reference)
//
#include <hip/hip_runtime.h>

#define NFEAT 512
#define HID 16
#define NCLS 40
#define BROWS 256        // rows per bucket
#define BCAP 16384       // fixed slots per bucket (mean fill 8184, 20+ sigma headroom)
#define PAIRS_BLOCKS 256 // pairs chunks; 12500 edges/chunk -> ~32/bucket = 128B runs

typedef unsigned int uint32;
typedef float f4 __attribute__((ext_vector_type(4)));

__device__ __forceinline__ uint32 f2bf(float f) {   // round-to-nearest-even bf16
    uint32 u = __float_as_uint(f);
    return (u + 0x7FFFu + ((u >> 16) & 1u)) >> 16;
}
__device__ __forceinline__ float bf2f(uint32 h) {
    return __uint_as_float(h << 16);
}

__global__ void k_zero(int* __restrict__ p, int m) {
    int i = blockIdx.x * blockDim.x + threadIdx.x;
    if (i < m) p[i] = 0;
}

// ---------------- fused: pairs binning (blocks 0..255) || layer-1 GEMM (rest) ------
// pairs: pk = (r&255)<<17 | c  into fixed bucket regions (single pass over edges)
// gemm : h1 = bf16( x @ W1 )   (UNSCALED -- dinv not yet available; agg1 scales)
__global__ __launch_bounds__(256, 4) void k_fused1(const float* __restrict__ x,
                                                   const float* __restrict__ W,
                                                   uint32* __restrict__ h1, int n,
                                                   const int* __restrict__ row,
                                                   const int* __restrict__ col,
                                                   int* __restrict__ bcur,
                                                   uint32* __restrict__ pairs,
                                                   int E, int nb) {
    __shared__ float smem[8704];   // gemm: padded W1 (34KB); pairs: hist+base (4KB)
    const int tid = threadIdx.x;

    if (blockIdx.x < PAIRS_BLOCKS) {
        int* lhist = (int*)smem;
        int* lbase = (int*)smem + 512;
        int chunk = (E + PAIRS_BLOCKS - 1) / PAIRS_BLOCKS;
        int s = blockIdx.x * chunk;
        int e = min(s + chunk, E);
        for (int b = tid; b < nb; b += 256) lhist[b] = 0;
        __syncthreads();
        for (int i = s + tid; i < e; i += 256)
            atomicAdd(&lhist[row[i] >> 8], 1);
        __syncthreads();
        for (int b = tid; b < nb; b += 256) {
            int h = lhist[b];
            lbase[b] = h ? atomicAdd(&bcur[b], h) : 0;
            lhist[b] = 0;   // reuse as local cursor
        }
        __syncthreads();
        for (int i = s + tid; i < e; i += 256) {
            int r = row[i], c = col[i];
            int b = r >> 8;
            int off = lbase[b] + atomicAdd(&lhist[b], 1);
            if (off < BCAP)
                pairs[(size_t)b * BCAP + off] = ((uint32)(r & 255) << 17) | (uint32)c;
        }
        return;
    }

    // ---- gemm branch ----
    float* Wl = smem;
    const int ks = tid & 7;       // k-slice
    const int g  = tid >> 3;      // row-group 0..31

#pragma unroll
    for (int i = 0; i < 8; i++) {
        int fidx = tid + i * 256;
        int k = fidx >> 2, j4 = fidx & 3;
        float4 v = reinterpret_cast<const float4*>(W)[fidx];
        *reinterpret_cast<float4*>(&Wl[k * 16 + (k >> 2) * 4 + j4 * 4]) = v;
    }
    __syncthreads();

    const int rbase = (blockIdx.x - PAIRS_BLOCKS) * 64 + g * 2;
    const int r0 = min(rbase, n - 1);       // clamp: OOB rows read row n-1, writes guarded
    const int r1 = min(rbase + 1, n - 1);
    const f4* xq0 = reinterpret_cast<const f4*>(x + (size_t)r0 * NFEAT);
    const f4* xq1 = reinterpret_cast<const f4*>(x + (size_t)r1 * NFEAT);

    float acc[2][16];
#pragma unroll
    for (int rr = 0; rr < 2; rr++)
#pragma unroll
        for (int j = 0; j < 16; j++) acc[rr][j] = 0.f;

    f4 xv[2], xn[2];
    xv[0] = __builtin_nontemporal_load(&xq0[ks]);
    xv[1] = __builtin_nontemporal_load(&xq1[ks]);

    for (int c = 0; c < 16; c++) {
        if (c < 15) {   // prefetch next chunk
            xn[0] = __builtin_nontemporal_load(&xq0[(c + 1) * 8 + ks]);
            xn[1] = __builtin_nontemporal_load(&xq1[(c + 1) * 8 + ks]);
        }
#pragma unroll
        for (int m = 0; m < 4; m++) {
            int k = c * 32 + ks * 4 + m;
            const float* wrow = &Wl[k * 16 + (k >> 2) * 4];
            float4 wv[4];
#pragma unroll
            for (int j4 = 0; j4 < 4; j4++)
                wv[j4] = *reinterpret_cast<const float4*>(wrow + j4 * 4);
#pragma unroll
            for (int rr = 0; rr < 2; rr++) {
                float xs = xv[rr][m];
#pragma unroll
                for (int j4 = 0; j4 < 4; j4++) {
                    acc[rr][j4 * 4 + 0] = fmaf(xs, wv[j4].x, acc[rr][j4 * 4 + 0]);
                    acc[rr][j4 * 4 + 1] = fmaf(xs, wv[j4].y, acc[rr][j4 * 4 + 1]);
                    acc[rr][j4 * 4 + 2] = fmaf(xs, wv[j4].z, acc[rr][j4 * 4 + 2]);
                    acc[rr][j4 * 4 + 3] = fmaf(xs, wv[j4].w, acc[rr][j4 * 4 + 3]);
                }
            }
        }
        xv[0] = xn[0];
        xv[1] = xn[1];
    }

#pragma unroll
    for (int off = 1; off < 8; off <<= 1)
#pragma unroll
        for (int rr = 0; rr < 2; rr++)
#pragma unroll
            for (int j = 0; j < 16; j++)
                acc[rr][j] += __shfl_xor(acc[rr][j], off, 8);

    if (ks == 0) {
#pragma unroll
        for (int rr = 0; rr < 2; rr++) {
            int r = rbase + rr;
            if (r < n) {
                uint32 us[8];
#pragma unroll
                for (int q = 0; q < 8; q++) {
                    uint32 lo = f2bf(acc[rr][q * 2]);
                    uint32 hi = f2bf(acc[rr][q * 2 + 1]);
                    us[q] = lo | (hi << 16);
                }
                uint4* o = reinterpret_cast<uint4*>(h1 + (size_t)r * 8);
                o[0] = make_uint4(us[0], us[1], us[2], us[3]);
                o[1] = make_uint4(us[4], us[5], us[6], us[7]);
            }
        }
    }
}

// ---------------- per-bucket row-hist + scan + dinv + CSR scatter ----------------
__global__ __launch_bounds__(256) void k_csr(const int* __restrict__ bcur,
                                             const uint32* __restrict__ pairs,
                                             int* __restrict__ csr,
                                             int* __restrict__ start, int* __restrict__ end,
                                             float* __restrict__ dinv, int n) {
    __shared__ int lhist[256];
    __shared__ int sm[256];
    __shared__ int lcur[256];
    int b = blockIdx.x;
    int base = b * BROWS;
    int i = base + threadIdx.x;
    int bo = b * BCAP;
    int cnt = min(bcur[b], BCAP);
    int e2 = bo + cnt;

    lhist[threadIdx.x] = 0;
    __syncthreads();
    for (int p = bo + (int)threadIdx.x; p < e2; p += 256)
        atomicAdd(&lhist[pairs[p] >> 17], 1);
    __syncthreads();
    int c = lhist[threadIdx.x];
    if (i < n) dinv[i] = rsqrtf((float)c + 1.0f);   // +1 = self loop
    sm[threadIdx.x] = c;
    __syncthreads();
    for (int off = 1; off < 256; off <<= 1) {
        int t = (threadIdx.x >= off) ? sm[threadIdx.x - off] : 0;
        __syncthreads();
        sm[threadIdx.x] += t;
        __syncthreads();
    }
    int excl = sm[threadIdx.x] - c;   // exclusive within bucket
    lcur[threadIdx.x] = excl;
    if (i < n) {
        start[i] = bo + excl;
        end[i]   = bo + excl + c;
    }
    __syncthreads();
    for (int p = bo + (int)threadIdx.x; p < e2; p += 256) {
        uint32 pk = pairs[p];
        int off = atomicAdd(&lcur[pk >> 17], 1);
        csr[bo + off] = (int)(pk & 0x1FFFFu);
    }
}

// ---------------- layer 1 aggregation + bias + relu; g2 = bf16(dinv ⊙ relu(z)) ----
// h1 is UNSCALED; scale each gathered neighbor by dinv[c] (L2-resident 400KB table).
__global__ __launch_bounds__(256) void k_agg1(const uint32* __restrict__ h1,
                                              const int* __restrict__ start,
                                              const int* __restrict__ end,
                                              const int* __restrict__ csr,
                                              const float* __restrict__ dinv,
                                              const float* __restrict__ b1,
                                              uint32* __restrict__ g2, int n) {
    int g = threadIdx.x >> 3;
    int l = threadIdx.x & 7;
    int r = blockIdx.x * 32 + g;
    if (r >= n) return;
    int s = start[r], e = end[r];
    float a0 = 0.f, a1 = 0.f;
    int p = s;
    for (; p + 8 <= e; p += 8) {
        int c[8];
#pragma unroll
        for (int u = 0; u < 8; u++) c[u] = csr[p + u];
        uint32 hv[8];
        float dv[8];
#pragma unroll
        for (int u = 0; u < 8; u++) hv[u] = h1[c[u] * 8 + l];
#pragma unroll
        for (int u = 0; u < 8; u++) dv[u] = dinv[c[u]];
#pragma unroll
        for (int u = 0; u < 8; u++) {
            a0 = fmaf(dv[u], bf2f(hv[u] & 0xFFFFu), a0);
            a1 = fmaf(dv[u], bf2f(hv[u] >> 16), a1);
        }
    }
    for (; p < e; p++) {
        int c = csr[p];
        uint32 h = h1[c * 8 + l];
        float dv = dinv[c];
        a0 = fmaf(dv, bf2f(h & 0xFFFFu), a0);
        a1 = fmaf(dv, bf2f(h >> 16), a1);
    }
    uint32 hs = h1[r * 8 + l];
    float dr = dinv[r];
    float z0 = fmaf(dr, fmaf(dr, bf2f(hs & 0xFFFFu), a0), b1[2 * l]);
    float z1 = fmaf(dr, fmaf(dr, bf2f(hs >> 16), a1), b1[2 * l + 1]);
    g2[r * 8 + l] = f2bf(dr * fmaxf(z0, 0.f)) | (f2bf(dr * fmaxf(z1, 0.f)) << 16);
}

// ---------------- layer 2 fused: aggregate g2 (prescaled), @W2 + b2 + log_softmax ----
__global__ __launch_bounds__(256) void k_agg2(const uint32* __restrict__ g2,
                                              const int* __restrict__ start,
                                              const int* __restrict__ end,
                                              const int* __restrict__ csr,
                                              const float* __restrict__ dinv,
                                              const float* __restrict__ W2,
                                              const float* __restrict__ b2,
                                              float* __restrict__ out, int n) {
    __shared__ float vsm[32][17];
    int g = threadIdx.x >> 3;
    int l = threadIdx.x & 7;
    int r = blockIdx.x * 32 + g;
    float a0 = 0.f, a1 = 0.f;
    if (r < n) {
        int s = start[r], e = end[r];
        int p = s;
        for (; p + 8 <= e; p += 8) {
            int c[8];
#pragma unroll
            for (int u = 0; u < 8; u++) c[u] = csr[p + u];
            uint32 hv[8];
#pragma unroll
            for (int u = 0; u < 8; u++) hv[u] = g2[c[u] * 8 + l];
#pragma unroll
            for (int u = 0; u < 8; u++) {
                a0 += bf2f(hv[u] & 0xFFFFu);
                a1 += bf2f(hv[u] >> 16);
            }
        }
        for (; p < e; p++) {
            uint32 h = g2[csr[p] * 8 + l];
            a0 += bf2f(h & 0xFFFFu);
            a1 += bf2f(h >> 16);
        }
        uint32 hs = g2[r * 8 + l];
        float dr = dinv[r];
        a0 = dr * (a0 + bf2f(hs & 0xFFFFu));
        a1 = dr * (a1 + bf2f(hs >> 16));
    }
    vsm[g][2 * l] = a0;
    vsm[g][2 * l + 1] = a1;
    __syncthreads();
    if (r >= n) return;

    float vloc[16];
#pragma unroll
    for (int k = 0; k < 16; k++) vloc[k] = vsm[g][k];

    float z[5];
#pragma unroll
    for (int i = 0; i < 5; i++) z[i] = b2[l + 8 * i];
#pragma unroll
    for (int k = 0; k < 16; k++) {
        float vk = vloc[k];
        const float* wk = W2 + k * NCLS;
#pragma unroll
        for (int i = 0; i < 5; i++) z[i] = fmaf(vk, wk[l + 8 * i], z[i]);
    }
    float m = z[0];
#pragma unroll
    for (int i = 1; i < 5; i++) m = fmaxf(m, z[i]);
#pragma unroll
    for (int off = 1; off < 8; off <<= 1) m = fmaxf(m, __shfl_xor(m, off, 8));
    float ssum = 0.f;
#pragma unroll
    for (int i = 0; i < 5; i++) ssum += __expf(z[i] - m);
#pragma unroll
    for (int off = 1; off < 8; off <<= 1) ssum += __shfl_xor(ssum, off, 8);
    float ls = m + logf(ssum);
    float* o = out + (size_t)r * NCLS;
#pragma unroll
    for (int i = 0; i < 5; i++) o[l + 8 * i] = z[i] - ls;
}

// ---------------- launch ----------------

extern "C" void kernel_launch(void* const* d_in, const int* in_sizes, int n_in,
                              void* d_out, int out_size, void* d_ws, size_t ws_size,
                              hipStream_t stream) {
    const float* x  = (const float*)d_in[0];
    const int*   ei = (const int*)d_in[1];
    const float* W1 = (const float*)d_in[2];
    const float* b1 = (const float*)d_in[3];
    const float* W2 = (const float*)d_in[4];
    const float* b2 = (const float*)d_in[5];

    const int n = in_sizes[0] / NFEAT;   // 100000
    const int E = in_sizes[1] / 2;       // 3200000
    const int* row = ei;
    const int* col = ei + E;
    const int nb = (n + BROWS - 1) / BROWS;   // 391

    char* w = (char*)d_ws;
    auto alloc = [&](size_t bytes) {
        void* p = (void*)w;
        w += (bytes + 255) & ~(size_t)255;
        return p;
    };
    int*    start = (int*)alloc((size_t)n * 4);
    int*    end   = (int*)alloc((size_t)n * 4);
    int*    bcur  = (int*)alloc(2048);
    float*  dinv  = (float*)alloc((size_t)n * 4);
    int*    csr   = (int*)alloc((size_t)nb * BCAP * 4);
    uint32* pairs = (uint32*)alloc((size_t)nb * BCAP * 4);
    uint32* h1    = (uint32*)alloc((size_t)n * HID * 2);
    uint32* g2    = (uint32*)alloc((size_t)n * HID * 2);

    k_zero<<<1, 512, 0, stream>>>(bcur, nb);
    k_fused1<<<PAIRS_BLOCKS + (n + 63) / 64, 256, 0, stream>>>(
        x, W1, h1, n, row, col, bcur, pairs, E, nb);
    k_csr<<<nb, 256, 0, stream>>>(bcur, pairs, csr, start, end, dinv, n);
    k_agg1<<<(n + 31) / 32, 256, 0, stream>>>(h1, start, end, csr, dinv, b1, g2, n);
    k_agg2<<<(n + 31) / 32, 256, 0, stream>>>(g2, start, end, csr, dinv, W2, b2,
                                              (float*)d_out, n);
}